// Round 10
// baseline (116.090 us; speedup 1.0000x reference)
//
#include <hip/hip_runtime.h>
#include <math.h>

#define NSEQ 4096
#define LFFT 8192
#define NT   512
static_assert(LFFT/16 == NT, "one radix-16 butterfly per thread");

// ---------- complex helpers ----------
__device__ __forceinline__ float2 cadd(float2 a, float2 b){ return make_float2(a.x+b.x, a.y+b.y); }
__device__ __forceinline__ float2 csub(float2 a, float2 b){ return make_float2(a.x-b.x, a.y-b.y); }
__device__ __forceinline__ float2 cmul(float2 a, float2 b){
  return make_float2(fmaf(a.x,b.x,-(a.y*b.y)), fmaf(a.x,b.y, a.y*b.x));
}
// a * conj(b)
__device__ __forceinline__ float2 cmulc(float2 a, float2 b){
  return make_float2(fmaf(a.x,b.x, a.y*b.y), fmaf(a.y,b.x,-(a.x*b.y)));
}
// z * (cr + i*ci)
__device__ __forceinline__ float2 mulk(float2 z, float cr, float ci){
  return make_float2(fmaf(z.x,cr,-(z.y*ci)), fmaf(z.x,ci, z.y*cr));
}
__device__ __forceinline__ float2 mulmi(float2 z){ return make_float2( z.y, -z.x); }
__device__ __forceinline__ float2 mulpi(float2 z){ return make_float2(-z.y,  z.x); }

#define C1 0.92387953251128675613f
#define S1 0.38268343236508977173f
#define RQ 0.70710678118654752440f

// LDS swizzle on float2 index. GF(2)-LINEAR: swz(a^b)=swz(a)^swz(b); for all
// stage patterns base+k*H == base|k*H, so swz(base+k*H)=swz(base)^swz(k*H)
// with swz(k*H) compile-time.
__device__ __host__ __forceinline__ constexpr int swz(int p){ return p ^ ((p>>4)&15); }

// W(k) = exp(-2*pi*i*k/8192), composed from two small tables (k < 8192)
__device__ __forceinline__ float2 twget(const float2* twHi, const float2* twLo, int k){
  return cmul(twHi[k>>6], twLo[k&63]);
}

__device__ __forceinline__ void init_tw(float2* twHi, float2* twLo){
  const float PI2 = 6.28318530717958647692f;
  int tid = threadIdx.x;
  if (tid < 128){
    float ang = -PI2 * (float)(tid*64) / (float)LFFT;
    float s, c; sincosf(ang, &s, &c);
    twHi[tid] = make_float2(c, s);
  } else if (tid < 192){
    int k = tid - 128;
    float ang = -PI2 * (float)k / (float)LFFT;
    float s, c; sincosf(ang, &s, &c);
    twLo[k] = make_float2(c, s);
  }
  __syncthreads();
}

// ---------- 16-point DFT cores (4x4 Cooley-Tukey, natural output index) ----------
// forward: f[k] <- sum_j f[j] W16^{jk}   (W16 = e^{-2pi i/16})
__device__ __forceinline__ void dft16_fwd(float2* f){
  float2 g[16]; // g[j1*4 + k1]
  #pragma unroll
  for (int j1=0;j1<4;++j1){
    float2 p0=f[j1], p1=f[j1+4], p2=f[j1+8], p3=f[j1+12];
    float2 t0=cadd(p0,p2), t1=csub(p0,p2), t2=cadd(p1,p3), t3=csub(p1,p3);
    g[j1*4+0]=cadd(t0,t2);
    g[j1*4+1]=make_float2(t1.x+t3.y, t1.y-t3.x);  // t1 - i t3
    g[j1*4+2]=csub(t0,t2);
    g[j1*4+3]=make_float2(t1.x-t3.y, t1.y+t3.x);  // t1 + i t3
  }
  // internal twiddles W16^{j1*k1} (negative convention)
  g[5]  = mulk(g[5],  C1,-S1);   // W16^1
  g[6]  = mulk(g[6],  RQ,-RQ);   // W16^2
  g[7]  = mulk(g[7],  S1,-C1);   // W16^3
  g[9]  = mulk(g[9],  RQ,-RQ);   // W16^2
  g[10] = mulmi(g[10]);          // W16^4
  g[11] = mulk(g[11],-RQ,-RQ);   // W16^6
  g[13] = mulk(g[13], S1,-C1);   // W16^3
  g[14] = mulk(g[14],-RQ,-RQ);   // W16^6
  g[15] = mulk(g[15],-C1, S1);   // W16^9
  #pragma unroll
  for (int k1=0;k1<4;++k1){
    float2 p0=g[k1], p1=g[4+k1], p2=g[8+k1], p3=g[12+k1];
    float2 t0=cadd(p0,p2), t1=csub(p0,p2), t2=cadd(p1,p3), t3=csub(p1,p3);
    f[k1]    = cadd(t0,t2);
    f[k1+4]  = make_float2(t1.x+t3.y, t1.y-t3.x);
    f[k1+8]  = csub(t0,t2);
    f[k1+12] = make_float2(t1.x-t3.y, t1.y+t3.x);
  }
}

// inverse: f[j] <- sum_k f[k] W16^{-jk with + sign} (conjugate network)
__device__ __forceinline__ void dft16_inv(float2* f){
  float2 e[16]; // e[k1*4 + j1]
  #pragma unroll
  for (int k1=0;k1<4;++k1){
    float2 p0=f[k1], p1=f[k1+4], p2=f[k1+8], p3=f[k1+12];
    float2 t0=cadd(p0,p2), t1=csub(p0,p2), t2=cadd(p1,p3), t3=csub(p1,p3);
    e[k1*4+0]=cadd(t0,t2);
    e[k1*4+1]=make_float2(t1.x-t3.y, t1.y+t3.x);  // t1 + i t3
    e[k1*4+2]=csub(t0,t2);
    e[k1*4+3]=make_float2(t1.x+t3.y, t1.y-t3.x);  // t1 - i t3
  }
  // internal conj twiddles W16^{+j1*k1}
  e[5]  = mulk(e[5],  C1, S1);
  e[6]  = mulk(e[6],  RQ, RQ);
  e[7]  = mulk(e[7],  S1, C1);
  e[9]  = mulk(e[9],  RQ, RQ);
  e[10] = mulpi(e[10]);
  e[11] = mulk(e[11],-RQ, RQ);
  e[13] = mulk(e[13], S1, C1);
  e[14] = mulk(e[14],-RQ, RQ);
  e[15] = mulk(e[15],-C1,-S1);
  #pragma unroll
  for (int j1=0;j1<4;++j1){
    float2 p0=e[j1], p1=e[4+j1], p2=e[8+j1], p3=e[12+j1];
    float2 t0=cadd(p0,p2), t1=csub(p0,p2), t2=cadd(p1,p3), t3=csub(p1,p3);
    f[j1]    = cadd(t0,t2);
    f[j1+4]  = make_float2(t1.x-t3.y, t1.y+t3.x);
    f[j1+8]  = csub(t0,t2);
    f[j1+12] = make_float2(t1.x+t3.y, t1.y-t3.x);
  }
}

// Build w^1..w^15 tree into w[] (w[0] unused)
__device__ __forceinline__ void wtree(float2 w1, float2* w){
  w[1]=w1;
  w[2]=cmul(w1,w1);
  w[3]=cmul(w[2],w1);
  w[4]=cmul(w[2],w[2]);
  w[5]=cmul(w[4],w1);
  w[6]=cmul(w[3],w[3]);
  w[7]=cmul(w[4],w[3]);
  w[8]=cmul(w[4],w[4]);
  w[9]=cmul(w[8],w1);
  w[10]=cmul(w[5],w[5]);
  w[11]=cmul(w[8],w[3]);
  w[12]=cmul(w[6],w[6]);
  w[13]=cmul(w[8],w[5]);
  w[14]=cmul(w[7],w[7]);
  w[15]=cmul(w[8],w[7]);
}

// ---------- radix-16 stages (one butterfly per thread) ----------
template<int H>
__device__ __forceinline__ void fwd_r16s(float2* z, const float2* twHi, const float2* twLo){
  constexpr int STEP = LFFT/(16*H);
  const int i = threadIdx.x;
  int pos = i & (H-1);
  int base = ((i - pos) << 4) + pos;
  int s = swz(base);
  float2 f[16];
  #pragma unroll
  for (int k=0;k<16;++k) f[k] = z[s ^ swz(k*H)];
  dft16_fwd(f);
  if constexpr (H > 1){
    float2 w[16];
    wtree(twget(twHi,twLo, pos*STEP), w);
    z[s] = f[0];
    #pragma unroll
    for (int k=1;k<16;++k) z[s ^ swz(k*H)] = cmul(f[k], w[k]);
  } else {
    #pragma unroll
    for (int k=0;k<16;++k) z[s ^ swz(k*H)] = f[k];
  }
  __syncthreads();
}

template<int H>
__device__ __forceinline__ void inv_r16s(float2* z, const float2* twHi, const float2* twLo){
  constexpr int STEP = LFFT/(16*H);
  const int i = threadIdx.x;
  int pos = i & (H-1);
  int base = ((i - pos) << 4) + pos;
  int s = swz(base);
  float2 f[16];
  f[0] = z[s];
  float2 w[16];
  wtree(twget(twHi,twLo, pos*STEP), w);
  #pragma unroll
  for (int k=1;k<16;++k) f[k] = cmulc(z[s ^ swz(k*H)], w[k]);
  dft16_inv(f);
  #pragma unroll
  for (int k=0;k<16;++k) z[s ^ swz(k*H)] = f[k];
  __syncthreads();
}

// Fused middle: fwd16(H=1) -> pointwise *Ahat -> inv16(H=1), register-resident.
__device__ __forceinline__ void mid16(float2* z, const float2* __restrict__ Ah){
  const int i = threadIdx.x;
  int base = i << 4;
  int s = swz(base);       // = base ^ (i&15);  swz(k)=k for k<16
  float2 f[16];
  #pragma unroll
  for (int k=0;k<16;++k) f[k] = z[s ^ k];
  dft16_fwd(f);
  #pragma unroll
  for (int k=0;k<16;++k) f[k] = cmul(f[k], Ah[base+k]);
  dft16_inv(f);
  #pragma unroll
  for (int k=0;k<16;++k) z[s ^ k] = f[k];
  __syncthreads();
}

// ---------- kernel A: DynamicPosBias MLP -> a[h][j] ----------
__device__ __forceinline__ void ln_relu16(const float* v, float* y, const float* g, const float* be){
  float mu = 0.f;
  #pragma unroll
  for (int p=0;p<16;++p) mu += v[p];
  mu *= (1.f/16.f);
  float var = 0.f;
  #pragma unroll
  for (int p=0;p<16;++p){ float d = v[p]-mu; var = fmaf(d,d,var); }
  var *= (1.f/16.f);
  float inv = 1.f / sqrtf(var + 1e-5f);
  #pragma unroll
  for (int p=0;p<16;++p){
    float t = fmaf((v[p]-mu)*inv, g[p], be[p]);
    y[p] = t > 0.f ? t : 0.f;
  }
}

__global__ void dpb_kernel(const float* __restrict__ W0, const float* __restrict__ b0,
                           const float* __restrict__ g1, const float* __restrict__ be1,
                           const float* __restrict__ W1, const float* __restrict__ b1,
                           const float* __restrict__ g2, const float* __restrict__ be2,
                           const float* __restrict__ W2, const float* __restrict__ b2,
                           const float* __restrict__ g3, const float* __restrict__ be3,
                           const float* __restrict__ W3, const float* __restrict__ b3,
                           float* __restrict__ a){
  int j = blockIdx.x*256 + threadIdx.x;   // 0..8191
  float t;
  if (j == 0 || j == NSEQ) t = 0.f;
  else if (j < NSEQ)       t = (float)j;
  else                     t = (float)(j - LFFT);   // negative side

  float v[16], y[16];
  #pragma unroll
  for (int p=0;p<16;++p) v[p] = fmaf(t, W0[p], b0[p]);
  ln_relu16(v, y, g1, be1);
  #pragma unroll
  for (int q=0;q<16;++q){ float s=b1[q];
    #pragma unroll
    for (int p=0;p<16;++p) s = fmaf(y[p], W1[p*16+q], s);
    v[q]=s; }
  ln_relu16(v, y, g2, be2);
  #pragma unroll
  for (int q=0;q<16;++q){ float s=b2[q];
    #pragma unroll
    for (int p=0;p<16;++p) s = fmaf(y[p], W2[p*16+q], s);
    v[q]=s; }
  ln_relu16(v, y, g3, be3);
  #pragma unroll
  for (int hh=0;hh<8;++hh){ float s=b3[hh];
    #pragma unroll
    for (int p=0;p<16;++p) s = fmaf(y[p], W3[p*8+hh], s);
    a[hh*LFFT + j] = s; }
}

// ---------- kernel B: forward FFT of a (per head), scrambled order, /L ----------
__global__ __launch_bounds__(NT, 4) void afft_kernel(const float* __restrict__ a,
                                                     float2* __restrict__ Ahat){
  __shared__ float2 z[LFFT];
  __shared__ float2 twHi[128];
  __shared__ float2 twLo[64];
  init_tw(twHi, twLo);
  const int h = blockIdx.x, tid = threadIdx.x;
  const float* ah = a + h*LFFT;
  #pragma unroll
  for (int r = 0; r < LFFT/NT; ++r){
    int j = r*NT + tid;
    z[swz(j)] = make_float2(ah[j], 0.f);
  }
  __syncthreads();
  // radix-2 DIF stage, full length 8192  (swz(4096)=4096)
  #pragma unroll
  for (int r = 0; r < LFFT/2/NT; ++r){
    int i = r*NT + tid;
    int s = swz(i);
    float2 u = z[s], v = z[s ^ 4096];
    z[s]        = cadd(u, v);
    z[s ^ 4096] = cmul(csub(u, v), twget(twHi,twLo,i));
  }
  __syncthreads();
  fwd_r16s<256>(z,twHi,twLo);
  fwd_r16s<16>(z,twHi,twLo);
  fwd_r16s<1>(z,twHi,twLo);
  const float sc = 1.f/(float)LFFT;
  float2* Ah = Ahat + h*LFFT;
  #pragma unroll
  for (int r = 0; r < LFFT/NT; ++r){
    int p = r*NT + tid;
    float2 v = z[swz(p)];
    Ah[p] = make_float2(v.x*sc, v.y*sc);
  }
}

// ---------- kernel C: packed-pair FFT convolution ----------
// launch_bounds (NT,4): VGPR cap 128; caps of 32 spill (rounds 3 & 7).
// Radix-16 stages: 7 LDS traversals / 7 barriers vs radix-8's 9.
__global__ __launch_bounds__(NT, 4) void conv_kernel(const float* __restrict__ x,
                                                     const float2* __restrict__ Ahat,
                                                     float* __restrict__ out){
  __shared__ float2 z[LFFT];
  __shared__ float2 twHi[128];
  __shared__ float2 twLo[64];
  init_tw(twHi, twLo);

  // XCD-aware swizzle: 32 e-pair blocks of the same (b,h) land on one XCD
  int bid = blockIdx.x;                       // 0..2047
  int logical = (bid & 7)*256 + (bid >> 3);
  int bh   = logical >> 5;                    // 0..63  (b*8+h)
  int pair = logical & 31;                    // 0..31
  int h    = bh & 7;
  const int tid = threadIdx.x;

  // load two adjacent e-columns as one complex sequence; fuse first radix-2
  // stage (upper half is zero padding): z[i]=v, z[i+4096]=v*W^i
  const float2* xp = (const float2*)x + (size_t)bh*NSEQ*32 + pair;
  #pragma unroll
  for (int r = 0; r < NSEQ/NT; ++r){
    int s = r*NT + tid;
    float2 v = xp[(size_t)s*32];
    int sw = swz(s);
    z[sw]        = v;
    z[sw ^ 4096] = cmul(v, twget(twHi,twLo,s));
  }
  __syncthreads();

  fwd_r16s<256>(z,twHi,twLo);
  fwd_r16s<16>(z,twHi,twLo);

  // fused middle: fwd16 + *Ahat + inv16 in registers (order matches afft)
  mid16(z, Ahat + h*LFFT);

  inv_r16s<16>(z,twHi,twLo);
  inv_r16s<256>(z,twHi,twLo);

  // final inverse radix-2 stage fused with the store (only low half needed)
  float2* op = (float2*)out + (size_t)bh*NSEQ*32 + pair;
  #pragma unroll
  for (int r = 0; r < NSEQ/NT; ++r){
    int i = r*NT + tid;
    int s = swz(i);
    float2 u = z[s];
    float2 v = cmulc(z[s ^ 4096], twget(twHi,twLo,i));
    op[(size_t)i*32] = cadd(u, v);
  }
}

// ---------- launch ----------
extern "C" void kernel_launch(void* const* d_in, const int* in_sizes, int n_in,
                              void* d_out, int out_size, void* d_ws, size_t ws_size,
                              hipStream_t stream){
  const float* x   = (const float*)d_in[0];
  const float* W0  = (const float*)d_in[1];
  const float* b0  = (const float*)d_in[2];
  const float* g1  = (const float*)d_in[3];
  const float* be1 = (const float*)d_in[4];
  const float* W1  = (const float*)d_in[5];
  const float* b1  = (const float*)d_in[6];
  const float* g2  = (const float*)d_in[7];
  const float* be2 = (const float*)d_in[8];
  const float* W2  = (const float*)d_in[9];
  const float* b2  = (const float*)d_in[10];
  const float* g3  = (const float*)d_in[11];
  const float* be3 = (const float*)d_in[12];
  const float* W3  = (const float*)d_in[13];
  const float* b3  = (const float*)d_in[14];

  float*  a    = (float*)d_ws;                                   // 8*8192 f32 = 256 KB
  float2* Ahat = (float2*)((char*)d_ws + (size_t)8*LFFT*sizeof(float)); // 8*8192 c64 = 512 KB
  float*  outp = (float*)d_out;

  dpb_kernel<<<LFFT/256, 256, 0, stream>>>(W0,b0,g1,be1,W1,b1,g2,be2,W2,b2,g3,be3,W3,b3, a);
  afft_kernel<<<8, NT, 0, stream>>>(a, Ahat);
  conv_kernel<<<2048, NT, 0, stream>>>(x, Ahat, outp);
}